// Round 10
// baseline (371.085 us; speedup 1.0000x reference)
//
#include <hip/hip_runtime.h>

#define NN 50000
#define NE 800000
#define DIM 128
#define NLAYERS 3

typedef __attribute__((ext_vector_type(8))) short bf16x8;
typedef __attribute__((ext_vector_type(4))) float f32x4;

__device__ __forceinline__ unsigned short f2bf_hi(float f) {
    unsigned int u = __float_as_uint(f);
    u += 0x7FFF + ((u >> 16) & 1);   // RTNE
    return (unsigned short)(u >> 16);
}
__device__ __forceinline__ float bf2f(unsigned short u) {
    return __uint_as_float(((unsigned int)u) << 16);
}

// ---------------- CSR build ----------------
__global__ __launch_bounds__(256) void rank_kernel(const int* __restrict__ tgt,
                                                   int* __restrict__ counts,
                                                   int* __restrict__ rank, int E) {
    int base = (blockIdx.x * 256 + threadIdx.x) * 4;
    if (base >= E) return;          // E % 4 == 0
    int4 t = *(const int4*)(tgt + base);
    int4 r;
    r.x = atomicAdd(&counts[t.x], 1);
    r.y = atomicAdd(&counts[t.y], 1);
    r.z = atomicAdd(&counts[t.z], 1);
    r.w = atomicAdd(&counts[t.w], 1);
    *(int4*)(rank + base) = r;
}

__global__ __launch_bounds__(256) void scan_partial_kernel(const int* __restrict__ counts,
                                                           int* __restrict__ psum, int n) {
    __shared__ int ws[4];
    int b = blockIdx.x, t = threadIdx.x;
    int idx = b * 1024 + t * 4;
    int v = 0;
    if (idx < n) {
        int4 c = *(const int4*)(counts + idx);
        v = c.x + c.y + c.z + c.w;
    }
#pragma unroll
    for (int o = 32; o > 0; o >>= 1) v += __shfl_xor(v, o);
    int lane = t & 63, wid = t >> 6;
    if (lane == 0) ws[wid] = v;
    __syncthreads();
    if (t == 0) psum[b] = ws[0] + ws[1] + ws[2] + ws[3];
}

__global__ __launch_bounds__(64) void scan_small_kernel(const int* __restrict__ psum,
                                                        int* __restrict__ pbase,
                                                        int* __restrict__ offsets,
                                                        int nb, int n) {
    int lane = threadIdx.x;
    int v = (lane < nb) ? psum[lane] : 0;
    int incl = v;
#pragma unroll
    for (int o = 1; o < 64; o <<= 1) {
        int t = __shfl_up(incl, o);
        if (lane >= o) incl += t;
    }
    if (lane < nb) pbase[lane] = incl - v;
    if (lane == 63) offsets[n] = incl;
}

__global__ __launch_bounds__(256) void scan_apply_kernel(const int* __restrict__ counts,
                                                         const int* __restrict__ pbase,
                                                         int* __restrict__ offsets, int n) {
    __shared__ int ws[4];
    int b = blockIdx.x, t = threadIdx.x;
    int lane = t & 63, wid = t >> 6;
    int idx = b * 1024 + t * 4;
    int4 c = make_int4(0, 0, 0, 0);
    if (idx < n) c = *(const int4*)(counts + idx);
    int tsum = c.x + c.y + c.z + c.w;
    int incl = tsum;
#pragma unroll
    for (int o = 1; o < 64; o <<= 1) {
        int tt = __shfl_up(incl, o);
        if (lane >= o) incl += tt;
    }
    if (lane == 63) ws[wid] = incl;
    __syncthreads();
    int wbase = pbase[b];
    for (int w = 0; w < wid; w++) wbase += ws[w];
    if (idx < n) {
        int e0 = wbase + incl - tsum;
        int4 o;
        o.x = e0;
        o.y = e0 + c.x;
        o.z = o.y + c.y;
        o.w = o.z + c.z;
        *(int4*)(offsets + idx) = o;
    }
}

__global__ __launch_bounds__(256) void scatter2_kernel(
    const int* __restrict__ src, const int* __restrict__ tgt,
    const float* __restrict__ ea, const int* __restrict__ rank,
    const int* __restrict__ offsets, int2* __restrict__ sedge, int E) {
    int base = (blockIdx.x * 256 + threadIdx.x) * 4;
    if (base >= E) return;
    int4 s = *(const int4*)(src + base);
    int4 t = *(const int4*)(tgt + base);
    int4 r = *(const int4*)(rank + base);
    float4 a = *(const float4*)(ea + base);
    sedge[offsets[t.x] + r.x] = make_int2(s.x << 8, __float_as_int(a.x));
    sedge[offsets[t.y] + r.y] = make_int2(s.y << 8, __float_as_int(a.y));
    sedge[offsets[t.z] + r.z] = make_int2(s.z << 8, __float_as_int(a.z));
    sedge[offsets[t.w] + r.w] = make_int2(s.w << 8, __float_as_int(a.w));
}

// ---------------- combined preprocessing: counts zero + x->bf16 + weight pack ----------------
__device__ __forceinline__ int packidx(int k, int c) {
    return (((k >> 5) << 3) + (c >> 4)) * 512 + (((k >> 3) & 3) << 7) + ((c & 15) << 3) + (k & 7);
}

#define ZERO_T 12500             // NN/4 int4 stores
#define XCVT_T 1600000           // NN*DIM/4

__global__ __launch_bounds__(256) void prep_kernel(
    int* __restrict__ counts,
    const float* __restrict__ x, unsigned short* __restrict__ xb,
    const float* __restrict__ w1, const float* __restrict__ w2, const float* __restrict__ fw,
    unsigned short* __restrict__ w1t_h, unsigned short* __restrict__ w1t_l,
    unsigned short* __restrict__ w2t_h, unsigned short* __restrict__ w2t_l,
    unsigned short* __restrict__ fwt_h, unsigned short* __restrict__ fwt_l) {
    int gid = blockIdx.x * 256 + threadIdx.x;
    if (gid < ZERO_T) {
        *(int4*)(counts + gid * 4) = make_int4(0, 0, 0, 0);
        return;
    }
    int g1 = gid - ZERO_T;
    if (g1 < XCVT_T) {
        int i = g1 * 4;
        float4 v = *(const float4*)(x + i);
        ushort4 o;
        o.x = f2bf_hi(v.x); o.y = f2bf_hi(v.y);
        o.z = f2bf_hi(v.z); o.w = f2bf_hi(v.w);
        *(ushort4*)(xb + i) = o;
        return;
    }
    int g0 = g1 - XCVT_T;
    float v; int oidx;
    unsigned short *oh, *ol;
    if (g0 < 49152) {                       // w1 [3][128][128]
        int l = g0 >> 14, rem = g0 & 16383, k = rem >> 7, c = rem & 127;
        v = w1[g0]; oidx = l * 16384 + packidx(k, c); oh = w1t_h; ol = w1t_l;
    } else if (g0 < 98304) {                // w2 [3][128][128]
        int g = g0 - 49152;
        int l = g >> 14, rem = g & 16383, k = rem >> 7, c = rem & 127;
        v = w2[g]; oidx = l * 16384 + packidx(k, c); oh = w2t_h; ol = w2t_l;
    } else if (g0 < 163840) {               // fw [512][128]
        int g = g0 - 98304;
        int k = g >> 7, c = g & 127;
        v = fw[g]; oidx = packidx(k, c); oh = fwt_h; ol = fwt_l;
    } else return;
    unsigned short h = f2bf_hi(v);
    float lo = v - bf2f(h);
    oh[oidx] = h;
    ol[oidx] = f2bf_hi(lo);
}

// ---------------- per-layer aggregation (round-7 form) ----------------
__global__ __launch_bounds__(256, 8) void agg_kernel(
    const unsigned short* __restrict__ hprev, const int* __restrict__ offs,
    const int2* __restrict__ sedge,
    const float* __restrict__ lw, const float* __restrict__ lb,
    const float* __restrict__ epsp, int layer,
    unsigned short* __restrict__ aggh, unsigned short* __restrict__ aggl, int N) {
    int g = threadIdx.x >> 4;          // group 0..15, one node each
    int r = threadIdx.x & 15;          // dim owner within group
    int node = blockIdx.x * 16 + g;
    if (node >= N) return;
    int d0 = r * 8;
    float lwv[8], lbv[8];
    *(float4*)&lwv[0] = *(const float4*)(lw + d0);
    *(float4*)&lwv[4] = *(const float4*)(lw + d0 + 4);
    *(float4*)&lbv[0] = *(const float4*)(lb + d0);
    *(float4*)&lbv[4] = *(const float4*)(lb + d0 + 4);
    const char* hb = (const char*)hprev + r * 16;

    int s0 = offs[node], s1 = offs[node + 1];
    int sm = s1 - 1;
    int cnt = s1 - s0;
    float a[8];
#pragma unroll
    for (int c = 0; c < 8; c++) a[c] = 0.f;

    int2 e0 = sedge[s0];
    int2 e1 = sedge[min(s0 + 1, sm)];
    int2 e2 = sedge[min(s0 + 2, sm)];
    int2 e3 = sedge[min(s0 + 3, sm)];
    uint4 h0 = *(const uint4*)(hb + (unsigned)e0.x);
    uint4 h1 = *(const uint4*)(hb + (unsigned)e1.x);
    uint4 h2 = *(const uint4*)(hb + (unsigned)e2.x);

    for (int it = s0; it < s1; ++it) {
        uint4 h3 = *(const uint4*)(hb + (unsigned)e3.x);
        int2 e4 = sedge[min(it + 4, sm)];
        float wgt = __int_as_float(e0.y);
        unsigned uu[4] = {h0.x, h0.y, h0.z, h0.w};
#pragma unroll
        for (int c = 0; c < 4; c++) {
            float f0 = __uint_as_float(uu[c] << 16);
            float f1 = __uint_as_float(uu[c] & 0xffff0000u);
            a[2 * c]     += fmaxf(f0 + fmaf(wgt, lwv[2 * c], lbv[2 * c]), 0.f);
            a[2 * c + 1] += fmaxf(f1 + fmaf(wgt, lwv[2 * c + 1], lbv[2 * c + 1]), 0.f);
        }
        e0 = e1; e1 = e2; e2 = e3; e3 = e4;
        h0 = h1; h1 = h2; h2 = h3;
    }

    float inv = 1.f / (float)cnt;
    float ge = 1.f + epsp[layer];
    uint4 hs = *(const uint4*)(hb + ((unsigned)node << 8));
    unsigned su[4] = {hs.x, hs.y, hs.z, hs.w};
    unsigned short hh[8], hl[8];
#pragma unroll
    for (int c = 0; c < 4; c++) {
        float f0 = __uint_as_float(su[c] << 16);
        float f1 = __uint_as_float(su[c] & 0xffff0000u);
        float v0 = a[2 * c] * inv + ge * f0;
        float v1 = a[2 * c + 1] * inv + ge * f1;
        unsigned short h0v = f2bf_hi(v0), h1v = f2bf_hi(v1);
        hh[2 * c] = h0v; hh[2 * c + 1] = h1v;
        hl[2 * c] = f2bf_hi(v0 - bf2f(h0v));
        hl[2 * c + 1] = f2bf_hi(v1 - bf2f(h1v));
    }
    unsigned short* ph = aggh + (size_t)node * DIM + d0;
    unsigned short* pl = aggl + (size_t)node * DIM + d0;
    *(ushort4*)ph       = *(const ushort4*)&hh[0];
    *(ushort4*)(ph + 4) = *(const ushort4*)&hh[4];
    *(ushort4*)pl       = *(const ushort4*)&hl[0];
    *(ushort4*)(pl + 4) = *(const ushort4*)&hl[4];
}

#define HSTR 136   // [64 nodes][136] bf16: 16B-aligned rows, uniform bank spread

// depth-1 register double-buffer load/compute macros (named buffers).
#define MLP1_LOAD(T, Bh_, Bl_, Ah_, Al_) do {                               \
    int k0_ = (T) * 32;                                                     \
    _Pragma("unroll")                                                       \
    for (int j_ = 0; j_ < 2; j_++) {                                        \
        size_t ro_ = (size_t)rowc[j_] * DIM + k0_ + q * 8;                  \
        Bh_[j_] = *(const bf16x8*)(ah_g + ro_);                             \
        Bl_[j_] = *(const bf16x8*)(al_g + ro_);                             \
    }                                                                       \
    _Pragma("unroll")                                                       \
    for (int i_ = 0; i_ < 4; i_++) {                                        \
        size_t co_ = ((size_t)((T) * 8 + wr * 4 + i_) << 9) + lane * 8;     \
        Ah_[i_] = *(const bf16x8*)(w1h + co_);                              \
        Al_[i_] = *(const bf16x8*)(w1l + co_);                              \
    }                                                                       \
} while (0)

#define MLP2_LOADW(T, Ah_, Al_) do {                                        \
    _Pragma("unroll")                                                       \
    for (int i_ = 0; i_ < 4; i_++) {                                        \
        size_t co_ = ((size_t)((T) * 8 + wr * 4 + i_) << 9) + lane * 8;     \
        Ah_[i_] = *(const bf16x8*)(w2h + co_);                              \
        Al_[i_] = *(const bf16x8*)(w2l + co_);                              \
    }                                                                       \
} while (0)

#define MLP2_LOADB(T, Bh_, Bl_) do {                                        \
    int k0_ = (T) * 32;                                                     \
    _Pragma("unroll")                                                       \
    for (int j_ = 0; j_ < 2; j_++) {                                        \
        int so_ = (wc * 32 + j_ * 16 + lr) * HSTR + k0_ + q * 8;            \
        Bh_[j_] = *(const bf16x8*)&s_hh[so_];                               \
        Bl_[j_] = *(const bf16x8*)&s_hl[so_];                               \
    }                                                                       \
} while (0)

#define MLP_MFMA(Bh_, Bl_, Ah_, Al_) do {                                   \
    _Pragma("unroll")                                                       \
    for (int i_ = 0; i_ < 4; i_++)                                          \
        _Pragma("unroll")                                                   \
        for (int j_ = 0; j_ < 2; j_++) {                                    \
            acc[i_][j_] = __builtin_amdgcn_mfma_f32_16x16x32_bf16(Ah_[i_], Bh_[j_], acc[i_][j_], 0, 0, 0); \
            acc[i_][j_] = __builtin_amdgcn_mfma_f32_16x16x32_bf16(Ah_[i_], Bl_[j_], acc[i_][j_], 0, 0, 0); \
            acc[i_][j_] = __builtin_amdgcn_mfma_f32_16x16x32_bf16(Al_[i_], Bh_[j_], acc[i_][j_], 0, 0, 0); \
        }                                                                   \
} while (0)

// body shared by mlp_fused / mlp_final_fused (phases 1-2)
#define MLP_PHASES_12()                                                     \
    f32x4 acc[4][2];                                                        \
    _Pragma("unroll")                                                       \
    for (int i = 0; i < 4; i++)                                             \
        _Pragma("unroll")                                                   \
        for (int j = 0; j < 2; j++) acc[i][j] = (f32x4)(0.f);               \
    bf16x8 pBh[2], pBl[2], pAh[4], pAl[4];                                  \
    bf16x8 qBh[2], qBl[2], qAh[4], qAl[4];                                  \
    MLP1_LOAD(0, pBh, pBl, pAh, pAl);                                       \
    MLP1_LOAD(1, qBh, qBl, qAh, qAl);                                       \
    MLP_MFMA(pBh, pBl, pAh, pAl);                                           \
    MLP1_LOAD(2, pBh, pBl, pAh, pAl);                                       \
    MLP_MFMA(qBh, qBl, qAh, qAl);                                           \
    MLP1_LOAD(3, qBh, qBl, qAh, qAl);                                       \
    MLP_MFMA(pBh, pBl, pAh, pAl);                                           \
    MLP_MFMA(qBh, qBl, qAh, qAl);                                           \
    MLP2_LOADW(0, pAh, pAl);                                                \
    _Pragma("unroll")                                                       \
    for (int i = 0; i < 4; i++) {                                           \
        int hc0 = wr * 64 + i * 16 + q * 4;                                 \
        float4 bv = *(const float4*)(b1 + hc0);                             \
        float bvr[4] = {bv.x, bv.y, bv.z, bv.w};                            \
        _Pragma("unroll")                                                   \
        for (int j = 0; j < 2; j++) {                                       \
            int nl = wc * 32 + j * 16 + lr;                                 \
            unsigned short hh[4], hl[4];                                    \
            _Pragma("unroll")                                               \
            for (int r = 0; r < 4; r++) {                                   \
                float v = fmaxf(acc[i][j][r] + bvr[r], 0.f);                \
                unsigned short h = f2bf_hi(v);                              \
                hh[r] = h;                                                  \
                hl[r] = f2bf_hi(v - bf2f(h));                               \
            }                                                               \
            *(ushort4*)&s_hh[nl * HSTR + hc0] = *(const ushort4*)&hh[0];    \
            *(ushort4*)&s_hl[nl * HSTR + hc0] = *(const ushort4*)&hl[0];    \
        }                                                                   \
    }                                                                       \
    __syncthreads();                                                        \
    _Pragma("unroll")                                                       \
    for (int i = 0; i < 4; i++)                                             \
        _Pragma("unroll")                                                   \
        for (int j = 0; j < 2; j++) acc[i][j] = (f32x4)(0.f);               \
    MLP2_LOADB(0, pBh, pBl);                                                \
    MLP2_LOADW(1, qAh, qAl);                                                \
    MLP2_LOADB(1, qBh, qBl);                                                \
    MLP_MFMA(pBh, pBl, pAh, pAl);                                           \
    MLP2_LOADW(2, pAh, pAl);                                                \
    MLP2_LOADB(2, pBh, pBl);                                                \
    MLP_MFMA(qBh, qBl, qAh, qAl);                                           \
    MLP2_LOADW(3, qAh, qAl);                                                \
    MLP2_LOADB(3, qBh, qBl);                                                \
    MLP_MFMA(pBh, pBl, pAh, pAl);                                           \
    MLP_MFMA(qBh, qBl, qAh, qAl);

// ---------------- fused 2-layer MLP (layers 0,1) ----------------
__global__ __launch_bounds__(256, 3) void mlp_fused(
    const unsigned short* __restrict__ ah_g, const unsigned short* __restrict__ al_g,
    const unsigned short* __restrict__ w1h, const unsigned short* __restrict__ w1l,
    const float* __restrict__ b1,
    const unsigned short* __restrict__ w2h, const unsigned short* __restrict__ w2l,
    const float* __restrict__ b2,
    unsigned short* __restrict__ out, int N) {
    __shared__ unsigned short s_hh[64 * HSTR], s_hl[64 * HSTR];
    int tid = threadIdx.x;
    int lane = tid & 63, w = tid >> 6;
    int q = lane >> 4, lr = lane & 15;
    int wr = w >> 1, wc = w & 1;
    int n0 = blockIdx.x * 64;
    int nb0 = n0 + wc * 32 + lr;            // + j*16
    int rowc[2];
    rowc[0] = min(nb0, N - 1);
    rowc[1] = min(nb0 + 16, N - 1);

    MLP_PHASES_12();

    // epilogue 2: bias (no relu), single bf16, vector 8B stores
#pragma unroll
    for (int i = 0; i < 4; i++) {
        int hc0 = wr * 64 + i * 16 + q * 4;
        float4 bv = *(const float4*)(b2 + hc0);
        float bvr[4] = {bv.x, bv.y, bv.z, bv.w};
#pragma unroll
        for (int j = 0; j < 2; j++) {
            int node = nb0 + j * 16;
            if (node < N) {
                unsigned short o[4];
#pragma unroll
                for (int r = 0; r < 4; r++) o[r] = f2bf_hi(acc[i][j][r] + bvr[r]);
                *(ushort4*)&out[(size_t)node * DIM + hc0] = *(const ushort4*)&o[0];
            }
        }
    }
}

// phase-3 helpers: B-only load (bulk prefetch), W-only load, MFMA variants
#define F3_LOADB(T, Bv_) do {                                               \
    const unsigned short* asrc_ = srcs3[(T) >> 2];                          \
    int kk_ = ((T) & 3) * 32;                                               \
    _Pragma("unroll")                                                       \
    for (int j_ = 0; j_ < 2; j_++) {                                        \
        size_t ro_ = (size_t)rowc[j_] * DIM + kk_ + q * 8;                  \
        Bv_[j_] = *(const bf16x8*)(asrc_ + ro_);                            \
    }                                                                       \
} while (0)

#define F3_LOADW(T, Wh_, Wl_) do {                                          \
    _Pragma("unroll")                                                       \
    for (int i_ = 0; i_ < 4; i_++) {                                        \
        size_t co_ = ((size_t)((T) * 8 + wr * 4 + i_) << 9) + lane * 8;     \
        Wh_[i_] = *(const bf16x8*)(fwh + co_);                              \
        Wl_[i_] = *(const bf16x8*)(fwl + co_);                              \
    }                                                                       \
} while (0)

#define FIN_MFMA(Bv_, Ah_, Al_) do {                                        \
    _Pragma("unroll")                                                       \
    for (int i_ = 0; i_ < 4; i_++)                                          \
        _Pragma("unroll")                                                   \
        for (int j_ = 0; j_ < 2; j_++) {                                    \
            acc[i_][j_] = __builtin_amdgcn_mfma_f32_16x16x32_bf16(Ah_[i_], Bv_[j_], acc[i_][j_], 0, 0, 0); \
            acc[i_][j_] = __builtin_amdgcn_mfma_f32_16x16x32_bf16(Al_[i_], Bv_[j_], acc[i_][j_], 0, 0, 0); \
        }                                                                   \
} while (0)

// LDS-sourced final k-step (h3 hi+lo from s_hh/s_hl), weights preloaded
#define F3_STEPL(T, Wh_, Wl_) do {                                          \
    int kk_ = ((T) - 12) * 32;                                              \
    bf16x8 Bh_[2], Bl_[2];                                                  \
    _Pragma("unroll")                                                       \
    for (int j_ = 0; j_ < 2; j_++) {                                        \
        int so_ = (wc * 32 + j_ * 16 + lr) * HSTR + kk_ + q * 8;            \
        Bh_[j_] = *(const bf16x8*)&s_hh[so_];                               \
        Bl_[j_] = *(const bf16x8*)&s_hl[so_];                               \
    }                                                                       \
    _Pragma("unroll")                                                       \
    for (int i_ = 0; i_ < 4; i_++)                                          \
        _Pragma("unroll")                                                   \
        for (int j_ = 0; j_ < 2; j_++) {                                    \
            acc[i_][j_] = __builtin_amdgcn_mfma_f32_16x16x32_bf16(Wh_[i_], Bh_[j_], acc[i_][j_], 0, 0, 0); \
            acc[i_][j_] = __builtin_amdgcn_mfma_f32_16x16x32_bf16(Wh_[i_], Bl_[j_], acc[i_][j_], 0, 0, 0); \
            acc[i_][j_] = __builtin_amdgcn_mfma_f32_16x16x32_bf16(Wl_[i_], Bh_[j_], acc[i_][j_], 0, 0, 0); \
        }                                                                   \
} while (0)

// ---------------- layer-2 MLP + final projection, fused ----------------
// Phase 3 bulk-B prefetch: ALL 8 global-B steps live in named registers
// before the first phase-3 MFMA (issued before the h3 barrier, so they fly
// during the barrier drain). Each buffer is recycled for steps 8..11 as it
// is consumed. Same loads, same accumulation order -> bit-identical.
__global__ __launch_bounds__(256, 3) void mlp_final_fused(
    const unsigned short* __restrict__ ah_g, const unsigned short* __restrict__ al_g,
    const unsigned short* __restrict__ w1h, const unsigned short* __restrict__ w1l,
    const float* __restrict__ b1,
    const unsigned short* __restrict__ w2h, const unsigned short* __restrict__ w2l,
    const float* __restrict__ b2,
    const unsigned short* __restrict__ xsrc, const unsigned short* __restrict__ h0p,
    const unsigned short* __restrict__ h1p,
    const unsigned short* __restrict__ fwh, const unsigned short* __restrict__ fwl,
    const float* __restrict__ fbias, float* __restrict__ out, int N) {
    __shared__ unsigned short s_hh[64 * HSTR], s_hl[64 * HSTR];
    int tid = threadIdx.x;
    int lane = tid & 63, w = tid >> 6;
    int q = lane >> 4, lr = lane & 15;
    int wr = w >> 1, wc = w & 1;
    int n0 = blockIdx.x * 64;
    int nb0 = n0 + wc * 32 + lr;
    int rowc[2];
    rowc[0] = min(nb0, N - 1);
    rowc[1] = min(nb0 + 16, N - 1);

    MLP_PHASES_12();

    // all phase-2 LDS reads complete before h3 overwrites the buffer
    __syncthreads();

    // epilogue 2: h3 = acc + b2 (no relu), hi/lo split -> LDS (no global store)
#pragma unroll
    for (int i = 0; i < 4; i++) {
        int hc0 = wr * 64 + i * 16 + q * 4;
        float4 bv = *(const float4*)(b2 + hc0);
        float bvr[4] = {bv.x, bv.y, bv.z, bv.w};
#pragma unroll
        for (int j = 0; j < 2; j++) {
            int nl = wc * 32 + j * 16 + lr;
            unsigned short hh[4], hl[4];
#pragma unroll
            for (int r = 0; r < 4; r++) {
                float v = acc[i][j][r] + bvr[r];
                unsigned short h = f2bf_hi(v);
                hh[r] = h;
                hl[r] = f2bf_hi(v - bf2f(h));
            }
            *(ushort4*)&s_hh[nl * HSTR + hc0] = *(const ushort4*)&hh[0];
            *(ushort4*)&s_hl[nl * HSTR + hc0] = *(const ushort4*)&hl[0];
        }
    }

    // phase 3: out = [xb|h0|h1|h3] @ fw + fb
#pragma unroll
    for (int i = 0; i < 4; i++)
#pragma unroll
        for (int j = 0; j < 2; j++) acc[i][j] = (f32x4)(0.f);

    const unsigned short* srcs3[3] = {xsrc, h0p, h1p};
    bf16x8 B0[2], B1[2], B2[2], B3[2], B4[2], B5[2], B6[2], B7[2];
    bf16x8 pWh[4], pWl[4], qWh[4], qWl[4];

    // bulk-issue: 8 B steps + 2 W steps in flight before the barrier
    // (global reads only -- no LDS hazard with the h3 writes above)
    F3_LOADB(0, B0); F3_LOADB(1, B1); F3_LOADB(2, B2); F3_LOADB(3, B3);
    F3_LOADB(4, B4); F3_LOADB(5, B5); F3_LOADB(6, B6); F3_LOADB(7, B7);
    F3_LOADW(0, pWh, pWl);
    F3_LOADW(1, qWh, qWl);
    __syncthreads();   // h3 LDS writes visible

    FIN_MFMA(B0, pWh, pWl); F3_LOADB(8, B0);  F3_LOADW(2, pWh, pWl);   // t=0
    FIN_MFMA(B1, qWh, qWl); F3_LOADB(9, B1);  F3_LOADW(3, qWh, qWl);   // t=1
    FIN_MFMA(B2, pWh, pWl); F3_LOADB(10, B2); F3_LOADW(4, pWh, pWl);   // t=2
    FIN_MFMA(B3, qWh, qWl); F3_LOADB(11, B3); F3_LOADW(5, qWh, qWl);   // t=3
    FIN_MFMA(B4, pWh, pWl); F3_LOADW(6, pWh, pWl);                     // t=4
    FIN_MFMA(B5, qWh, qWl); F3_LOADW(7, qWh, qWl);                     // t=5
    FIN_MFMA(B6, pWh, pWl); F3_LOADW(8, pWh, pWl);                     // t=6
    FIN_MFMA(B7, qWh, qWl); F3_LOADW(9, qWh, qWl);                     // t=7
    FIN_MFMA(B0, pWh, pWl); F3_LOADW(10, pWh, pWl);                    // t=8
    FIN_MFMA(B1, qWh, qWl); F3_LOADW(11, qWh, qWl);                    // t=9
    FIN_MFMA(B2, pWh, pWl); F3_LOADW(12, pWh, pWl);                    // t=10
    FIN_MFMA(B3, qWh, qWl); F3_LOADW(13, qWh, qWl);                    // t=11
    F3_STEPL(12, pWh, pWl); F3_LOADW(14, pWh, pWl);                    // t=12
    F3_STEPL(13, qWh, qWl); F3_LOADW(15, qWh, qWl);                    // t=13
    F3_STEPL(14, pWh, pWl);                                            // t=14
    F3_STEPL(15, qWh, qWl);                                            // t=15

    // final epilogue: fp32 + bias
#pragma unroll
    for (int i = 0; i < 4; i++) {
        int hc0 = wr * 64 + i * 16 + q * 4;
        float4 bv = *(const float4*)(fbias + hc0);
        float bvr[4] = {bv.x, bv.y, bv.z, bv.w};
#pragma unroll
        for (int j = 0; j < 2; j++) {
            int node = nb0 + j * 16;
            if (node < N) {
                float4 o;
                o.x = acc[i][j][0] + bvr[0];
                o.y = acc[i][j][1] + bvr[1];
                o.z = acc[i][j][2] + bvr[2];
                o.w = acc[i][j][3] + bvr[3];
                *(float4*)&out[(size_t)node * DIM + hc0] = o;
            }
        }
    }
}

extern "C" void kernel_launch(void* const* d_in, const int* in_sizes, int n_in,
                              void* d_out, int out_size, void* d_ws, size_t ws_size,
                              hipStream_t stream) {
    const float* x   = (const float*)d_in[0];
    const int* edge_index = (const int*)d_in[1];
    const float* ea  = (const float*)d_in[2];
    const float* lw  = (const float*)d_in[3];
    const float* lb  = (const float*)d_in[4];
    const float* eps = (const float*)d_in[5];
    const float* w1  = (const float*)d_in[6];
    const float* b1  = (const float*)d_in[7];
    const float* w2  = (const float*)d_in[8];
    const float* b2  = (const float*)d_in[9];
    const float* fw  = (const float*)d_in[10];
    const float* fb  = (const float*)d_in[11];
    float* out = (float*)d_out;

    const int N = NN, E = NE;
    const int* src = edge_index;
    const int* tgt = edge_index + E;
    const int NB = (N + 1023) / 1024;  // 49

    char* ws = (char*)d_ws;
    size_t off = 0;
    auto alloc = [&](size_t bytes) {
        void* p = ws + off;
        off += (bytes + 255) & ~(size_t)255;
        return p;
    };
    int*   counts  = (int*)alloc((size_t)N * 4);
    int*   offsets = (int*)alloc((size_t)(N + 1) * 4);
    int*   rank    = (int*)alloc((size_t)E * 4);
    int*   psum    = (int*)alloc((size_t)NB * 4);
    int*   pbase   = (int*)alloc((size_t)NB * 4);
    int2*  sedge   = (int2*)alloc((size_t)E * 8);
    unsigned short* w1t_h = (unsigned short*)alloc(49152 * 2);
    unsigned short* w1t_l = (unsigned short*)alloc(49152 * 2);
    unsigned short* w2t_h = (unsigned short*)alloc(49152 * 2);
    unsigned short* w2t_l = (unsigned short*)alloc(49152 * 2);
    unsigned short* fwt_h = (unsigned short*)alloc(65536 * 2);
    unsigned short* fwt_l = (unsigned short*)alloc(65536 * 2);
    unsigned short* xb    = (unsigned short*)alloc((size_t)N * DIM * 2);
    unsigned short* hbuf[2];
    for (int i = 0; i < 2; i++) hbuf[i] = (unsigned short*)alloc((size_t)N * DIM * 2);
    unsigned short* aggh = (unsigned short*)alloc((size_t)N * DIM * 2);
    unsigned short* aggl = (unsigned short*)alloc((size_t)N * DIM * 2);
    (void)ws_size; (void)in_sizes; (void)n_in; (void)out_size;

    const int PREP_T = ZERO_T + XCVT_T + 163840;
    prep_kernel<<<(PREP_T + 255) / 256, 256, 0, stream>>>(
        counts, x, xb, w1, w2, fw, w1t_h, w1t_l, w2t_h, w2t_l, fwt_h, fwt_l);
    rank_kernel<<<(E / 4 + 255) / 256, 256, 0, stream>>>(tgt, counts, rank, E);
    scan_partial_kernel<<<NB, 256, 0, stream>>>(counts, psum, N);
    scan_small_kernel<<<1, 64, 0, stream>>>(psum, pbase, offsets, NB, N);
    scan_apply_kernel<<<NB, 256, 0, stream>>>(counts, pbase, offsets, N);
    scatter2_kernel<<<(E / 4 + 255) / 256, 256, 0, stream>>>(src, tgt, ea, rank, offsets, sedge, E);

    const int GB = (N + 63) / 64;   // 782
    const int AB = (N + 15) / 16;   // 3125
    for (int l = 0; l < 2; l++) {
        const unsigned short* hin = (l == 0) ? xb : hbuf[l - 1];
        agg_kernel<<<AB, 256, 0, stream>>>(hin, offsets, sedge,
            lw + l * DIM, lb + l * DIM, eps, l, aggh, aggl, N);
        mlp_fused<<<GB, 256, 0, stream>>>(
            aggh, aggl,
            w1t_h + l * 16384, w1t_l + l * 16384, b1 + l * DIM,
            w2t_h + l * 16384, w2t_l + l * 16384, b2 + l * DIM,
            hbuf[l], N);
    }
    // layer 2 aggregation + fused MLP+final
    agg_kernel<<<AB, 256, 0, stream>>>(hbuf[1], offsets, sedge,
        lw + 2 * DIM, lb + 2 * DIM, eps, 2, aggh, aggl, N);
    mlp_final_fused<<<GB, 256, 0, stream>>>(
        aggh, aggl,
        w1t_h + 2 * 16384, w1t_l + 2 * 16384, b1 + 2 * DIM,
        w2t_h + 2 * 16384, w2t_l + 2 * 16384, b2 + 2 * DIM,
        xb, hbuf[0], hbuf[1], fwt_h, fwt_l, fb, out, N);
}

// Round 11
// 353.425 us; speedup vs baseline: 1.0500x; 1.0500x over previous
//
#include <hip/hip_runtime.h>

#define NN 50000
#define NE 800000
#define DIM 128
#define NLAYERS 3

typedef __attribute__((ext_vector_type(8))) short bf16x8;
typedef __attribute__((ext_vector_type(4))) float f32x4;

__device__ __forceinline__ unsigned short f2bf_hi(float f) {
    unsigned int u = __float_as_uint(f);
    u += 0x7FFF + ((u >> 16) & 1);   // RTNE
    return (unsigned short)(u >> 16);
}
__device__ __forceinline__ float bf2f(unsigned short u) {
    return __uint_as_float(((unsigned int)u) << 16);
}

// ---------------- CSR build ----------------
__global__ __launch_bounds__(256) void rank_kernel(const int* __restrict__ tgt,
                                                   int* __restrict__ counts,
                                                   int* __restrict__ rank, int E) {
    int base = (blockIdx.x * 256 + threadIdx.x) * 4;
    if (base >= E) return;          // E % 4 == 0
    int4 t = *(const int4*)(tgt + base);
    int4 r;
    r.x = atomicAdd(&counts[t.x], 1);
    r.y = atomicAdd(&counts[t.y], 1);
    r.z = atomicAdd(&counts[t.z], 1);
    r.w = atomicAdd(&counts[t.w], 1);
    *(int4*)(rank + base) = r;
}

__global__ __launch_bounds__(256) void scan_partial_kernel(const int* __restrict__ counts,
                                                           int* __restrict__ psum, int n) {
    __shared__ int ws[4];
    int b = blockIdx.x, t = threadIdx.x;
    int idx = b * 1024 + t * 4;
    int v = 0;
    if (idx < n) {
        int4 c = *(const int4*)(counts + idx);
        v = c.x + c.y + c.z + c.w;
    }
#pragma unroll
    for (int o = 32; o > 0; o >>= 1) v += __shfl_xor(v, o);
    int lane = t & 63, wid = t >> 6;
    if (lane == 0) ws[wid] = v;
    __syncthreads();
    if (t == 0) psum[b] = ws[0] + ws[1] + ws[2] + ws[3];
}

__global__ __launch_bounds__(64) void scan_small_kernel(const int* __restrict__ psum,
                                                        int* __restrict__ pbase,
                                                        int* __restrict__ offsets,
                                                        int nb, int n) {
    int lane = threadIdx.x;
    int v = (lane < nb) ? psum[lane] : 0;
    int incl = v;
#pragma unroll
    for (int o = 1; o < 64; o <<= 1) {
        int t = __shfl_up(incl, o);
        if (lane >= o) incl += t;
    }
    if (lane < nb) pbase[lane] = incl - v;
    if (lane == 63) offsets[n] = incl;
}

__global__ __launch_bounds__(256) void scan_apply_kernel(const int* __restrict__ counts,
                                                         const int* __restrict__ pbase,
                                                         int* __restrict__ offsets, int n) {
    __shared__ int ws[4];
    int b = blockIdx.x, t = threadIdx.x;
    int lane = t & 63, wid = t >> 6;
    int idx = b * 1024 + t * 4;
    int4 c = make_int4(0, 0, 0, 0);
    if (idx < n) c = *(const int4*)(counts + idx);
    int tsum = c.x + c.y + c.z + c.w;
    int incl = tsum;
#pragma unroll
    for (int o = 1; o < 64; o <<= 1) {
        int tt = __shfl_up(incl, o);
        if (lane >= o) incl += tt;
    }
    if (lane == 63) ws[wid] = incl;
    __syncthreads();
    int wbase = pbase[b];
    for (int w = 0; w < wid; w++) wbase += ws[w];
    if (idx < n) {
        int e0 = wbase + incl - tsum;
        int4 o;
        o.x = e0;
        o.y = e0 + c.x;
        o.z = o.y + c.y;
        o.w = o.z + c.z;
        *(int4*)(offsets + idx) = o;
    }
}

__global__ __launch_bounds__(256) void scatter2_kernel(
    const int* __restrict__ src, const int* __restrict__ tgt,
    const float* __restrict__ ea, const int* __restrict__ rank,
    const int* __restrict__ offsets, int2* __restrict__ sedge, int E) {
    int base = (blockIdx.x * 256 + threadIdx.x) * 4;
    if (base >= E) return;
    int4 s = *(const int4*)(src + base);
    int4 t = *(const int4*)(tgt + base);
    int4 r = *(const int4*)(rank + base);
    float4 a = *(const float4*)(ea + base);
    sedge[offsets[t.x] + r.x] = make_int2(s.x << 8, __float_as_int(a.x));
    sedge[offsets[t.y] + r.y] = make_int2(s.y << 8, __float_as_int(a.y));
    sedge[offsets[t.z] + r.z] = make_int2(s.z << 8, __float_as_int(a.z));
    sedge[offsets[t.w] + r.w] = make_int2(s.w << 8, __float_as_int(a.w));
}

// ---------------- combined preprocessing: counts zero + x->bf16 + weight pack ----------------
__device__ __forceinline__ int packidx(int k, int c) {
    return (((k >> 5) << 3) + (c >> 4)) * 512 + (((k >> 3) & 3) << 7) + ((c & 15) << 3) + (k & 7);
}

#define ZERO_T 12500             // NN/4 int4 stores
#define XCVT_T 1600000           // NN*DIM/4

__global__ __launch_bounds__(256) void prep_kernel(
    int* __restrict__ counts,
    const float* __restrict__ x, unsigned short* __restrict__ xb,
    const float* __restrict__ w1, const float* __restrict__ w2, const float* __restrict__ fw,
    unsigned short* __restrict__ w1t_h, unsigned short* __restrict__ w1t_l,
    unsigned short* __restrict__ w2t_h, unsigned short* __restrict__ w2t_l,
    unsigned short* __restrict__ fwt_h, unsigned short* __restrict__ fwt_l) {
    int gid = blockIdx.x * 256 + threadIdx.x;
    if (gid < ZERO_T) {
        *(int4*)(counts + gid * 4) = make_int4(0, 0, 0, 0);
        return;
    }
    int g1 = gid - ZERO_T;
    if (g1 < XCVT_T) {
        int i = g1 * 4;
        float4 v = *(const float4*)(x + i);
        ushort4 o;
        o.x = f2bf_hi(v.x); o.y = f2bf_hi(v.y);
        o.z = f2bf_hi(v.z); o.w = f2bf_hi(v.w);
        *(ushort4*)(xb + i) = o;
        return;
    }
    int g0 = g1 - XCVT_T;
    float v; int oidx;
    unsigned short *oh, *ol;
    if (g0 < 49152) {                       // w1 [3][128][128]
        int l = g0 >> 14, rem = g0 & 16383, k = rem >> 7, c = rem & 127;
        v = w1[g0]; oidx = l * 16384 + packidx(k, c); oh = w1t_h; ol = w1t_l;
    } else if (g0 < 98304) {                // w2 [3][128][128]
        int g = g0 - 49152;
        int l = g >> 14, rem = g & 16383, k = rem >> 7, c = rem & 127;
        v = w2[g]; oidx = l * 16384 + packidx(k, c); oh = w2t_h; ol = w2t_l;
    } else if (g0 < 163840) {               // fw [512][128]
        int g = g0 - 98304;
        int k = g >> 7, c = g & 127;
        v = fw[g]; oidx = packidx(k, c); oh = fwt_h; ol = fwt_l;
    } else return;
    unsigned short h = f2bf_hi(v);
    float lo = v - bf2f(h);
    oh[oidx] = h;
    ol[oidx] = f2bf_hi(lo);
}

// ---------------- per-layer aggregation (round-7 form) ----------------
__global__ __launch_bounds__(256, 8) void agg_kernel(
    const unsigned short* __restrict__ hprev, const int* __restrict__ offs,
    const int2* __restrict__ sedge,
    const float* __restrict__ lw, const float* __restrict__ lb,
    const float* __restrict__ epsp, int layer,
    unsigned short* __restrict__ aggh, unsigned short* __restrict__ aggl, int N) {
    int g = threadIdx.x >> 4;          // group 0..15, one node each
    int r = threadIdx.x & 15;          // dim owner within group
    int node = blockIdx.x * 16 + g;
    if (node >= N) return;
    int d0 = r * 8;
    float lwv[8], lbv[8];
    *(float4*)&lwv[0] = *(const float4*)(lw + d0);
    *(float4*)&lwv[4] = *(const float4*)(lw + d0 + 4);
    *(float4*)&lbv[0] = *(const float4*)(lb + d0);
    *(float4*)&lbv[4] = *(const float4*)(lb + d0 + 4);
    const char* hb = (const char*)hprev + r * 16;

    int s0 = offs[node], s1 = offs[node + 1];
    int sm = s1 - 1;
    int cnt = s1 - s0;
    float a[8];
#pragma unroll
    for (int c = 0; c < 8; c++) a[c] = 0.f;

    int2 e0 = sedge[s0];
    int2 e1 = sedge[min(s0 + 1, sm)];
    int2 e2 = sedge[min(s0 + 2, sm)];
    int2 e3 = sedge[min(s0 + 3, sm)];
    uint4 h0 = *(const uint4*)(hb + (unsigned)e0.x);
    uint4 h1 = *(const uint4*)(hb + (unsigned)e1.x);
    uint4 h2 = *(const uint4*)(hb + (unsigned)e2.x);

    for (int it = s0; it < s1; ++it) {
        uint4 h3 = *(const uint4*)(hb + (unsigned)e3.x);
        int2 e4 = sedge[min(it + 4, sm)];
        float wgt = __int_as_float(e0.y);
        unsigned uu[4] = {h0.x, h0.y, h0.z, h0.w};
#pragma unroll
        for (int c = 0; c < 4; c++) {
            float f0 = __uint_as_float(uu[c] << 16);
            float f1 = __uint_as_float(uu[c] & 0xffff0000u);
            a[2 * c]     += fmaxf(f0 + fmaf(wgt, lwv[2 * c], lbv[2 * c]), 0.f);
            a[2 * c + 1] += fmaxf(f1 + fmaf(wgt, lwv[2 * c + 1], lbv[2 * c + 1]), 0.f);
        }
        e0 = e1; e1 = e2; e2 = e3; e3 = e4;
        h0 = h1; h1 = h2; h2 = h3;
    }

    float inv = 1.f / (float)cnt;
    float ge = 1.f + epsp[layer];
    uint4 hs = *(const uint4*)(hb + ((unsigned)node << 8));
    unsigned su[4] = {hs.x, hs.y, hs.z, hs.w};
    unsigned short hh[8], hl[8];
#pragma unroll
    for (int c = 0; c < 4; c++) {
        float f0 = __uint_as_float(su[c] << 16);
        float f1 = __uint_as_float(su[c] & 0xffff0000u);
        float v0 = a[2 * c] * inv + ge * f0;
        float v1 = a[2 * c + 1] * inv + ge * f1;
        unsigned short h0v = f2bf_hi(v0), h1v = f2bf_hi(v1);
        hh[2 * c] = h0v; hh[2 * c + 1] = h1v;
        hl[2 * c] = f2bf_hi(v0 - bf2f(h0v));
        hl[2 * c + 1] = f2bf_hi(v1 - bf2f(h1v));
    }
    unsigned short* ph = aggh + (size_t)node * DIM + d0;
    unsigned short* pl = aggl + (size_t)node * DIM + d0;
    *(ushort4*)ph       = *(const ushort4*)&hh[0];
    *(ushort4*)(ph + 4) = *(const ushort4*)&hh[4];
    *(ushort4*)pl       = *(const ushort4*)&hl[0];
    *(ushort4*)(pl + 4) = *(const ushort4*)&hl[4];
}

#define HSTR 136   // [64 nodes][136] bf16: 16B-aligned rows, uniform bank spread

// depth-1 register double-buffer load/compute macros (named buffers).
#define MLP1_LOAD(T, Bh_, Bl_, Ah_, Al_) do {                               \
    int k0_ = (T) * 32;                                                     \
    _Pragma("unroll")                                                       \
    for (int j_ = 0; j_ < 2; j_++) {                                        \
        size_t ro_ = (size_t)rowc[j_] * DIM + k0_ + q * 8;                  \
        Bh_[j_] = *(const bf16x8*)(ah_g + ro_);                             \
        Bl_[j_] = *(const bf16x8*)(al_g + ro_);                             \
    }                                                                       \
    _Pragma("unroll")                                                       \
    for (int i_ = 0; i_ < 4; i_++) {                                        \
        size_t co_ = ((size_t)((T) * 8 + wr * 4 + i_) << 9) + lane * 8;     \
        Ah_[i_] = *(const bf16x8*)(w1h + co_);                              \
        Al_[i_] = *(const bf16x8*)(w1l + co_);                              \
    }                                                                       \
} while (0)

#define MLP2_LOADW(T, Ah_, Al_) do {                                        \
    _Pragma("unroll")                                                       \
    for (int i_ = 0; i_ < 4; i_++) {                                        \
        size_t co_ = ((size_t)((T) * 8 + wr * 4 + i_) << 9) + lane * 8;     \
        Ah_[i_] = *(const bf16x8*)(w2h + co_);                              \
        Al_[i_] = *(const bf16x8*)(w2l + co_);                              \
    }                                                                       \
} while (0)

#define MLP2_LOADB(T, Bh_, Bl_) do {                                        \
    int k0_ = (T) * 32;                                                     \
    _Pragma("unroll")                                                       \
    for (int j_ = 0; j_ < 2; j_++) {                                        \
        int so_ = (wc * 32 + j_ * 16 + lr) * HSTR + k0_ + q * 8;            \
        Bh_[j_] = *(const bf16x8*)&s_hh[so_];                               \
        Bl_[j_] = *(const bf16x8*)&s_hl[so_];                               \
    }                                                                       \
} while (0)

#define MLP_MFMA(Bh_, Bl_, Ah_, Al_) do {                                   \
    _Pragma("unroll")                                                       \
    for (int i_ = 0; i_ < 4; i_++)                                          \
        _Pragma("unroll")                                                   \
        for (int j_ = 0; j_ < 2; j_++) {                                    \
            acc[i_][j_] = __builtin_amdgcn_mfma_f32_16x16x32_bf16(Ah_[i_], Bh_[j_], acc[i_][j_], 0, 0, 0); \
            acc[i_][j_] = __builtin_amdgcn_mfma_f32_16x16x32_bf16(Ah_[i_], Bl_[j_], acc[i_][j_], 0, 0, 0); \
            acc[i_][j_] = __builtin_amdgcn_mfma_f32_16x16x32_bf16(Al_[i_], Bh_[j_], acc[i_][j_], 0, 0, 0); \
        }                                                                   \
} while (0)

// body shared by mlp_fused / mlp_final_fused (phases 1-2)
#define MLP_PHASES_12()                                                     \
    f32x4 acc[4][2];                                                        \
    _Pragma("unroll")                                                       \
    for (int i = 0; i < 4; i++)                                             \
        _Pragma("unroll")                                                   \
        for (int j = 0; j < 2; j++) acc[i][j] = (f32x4)(0.f);               \
    bf16x8 pBh[2], pBl[2], pAh[4], pAl[4];                                  \
    bf16x8 qBh[2], qBl[2], qAh[4], qAl[4];                                  \
    MLP1_LOAD(0, pBh, pBl, pAh, pAl);                                       \
    MLP1_LOAD(1, qBh, qBl, qAh, qAl);                                       \
    MLP_MFMA(pBh, pBl, pAh, pAl);                                           \
    MLP1_LOAD(2, pBh, pBl, pAh, pAl);                                       \
    MLP_MFMA(qBh, qBl, qAh, qAl);                                           \
    MLP1_LOAD(3, qBh, qBl, qAh, qAl);                                       \
    MLP_MFMA(pBh, pBl, pAh, pAl);                                           \
    MLP_MFMA(qBh, qBl, qAh, qAl);                                           \
    MLP2_LOADW(0, pAh, pAl);                                                \
    _Pragma("unroll")                                                       \
    for (int i = 0; i < 4; i++) {                                           \
        int hc0 = wr * 64 + i * 16 + q * 4;                                 \
        float4 bv = *(const float4*)(b1 + hc0);                             \
        float bvr[4] = {bv.x, bv.y, bv.z, bv.w};                            \
        _Pragma("unroll")                                                   \
        for (int j = 0; j < 2; j++) {                                       \
            int nl = wc * 32 + j * 16 + lr;                                 \
            unsigned short hh[4], hl[4];                                    \
            _Pragma("unroll")                                               \
            for (int r = 0; r < 4; r++) {                                   \
                float v = fmaxf(acc[i][j][r] + bvr[r], 0.f);                \
                unsigned short h = f2bf_hi(v);                              \
                hh[r] = h;                                                  \
                hl[r] = f2bf_hi(v - bf2f(h));                               \
            }                                                               \
            *(ushort4*)&s_hh[nl * HSTR + hc0] = *(const ushort4*)&hh[0];    \
            *(ushort4*)&s_hl[nl * HSTR + hc0] = *(const ushort4*)&hl[0];    \
        }                                                                   \
    }                                                                       \
    __syncthreads();                                                        \
    _Pragma("unroll")                                                       \
    for (int i = 0; i < 4; i++)                                             \
        _Pragma("unroll")                                                   \
        for (int j = 0; j < 2; j++) acc[i][j] = (f32x4)(0.f);               \
    MLP2_LOADB(0, pBh, pBl);                                                \
    MLP2_LOADW(1, qAh, qAl);                                                \
    MLP2_LOADB(1, qBh, qBl);                                                \
    MLP_MFMA(pBh, pBl, pAh, pAl);                                           \
    MLP2_LOADW(2, pAh, pAl);                                                \
    MLP2_LOADB(2, pBh, pBl);                                                \
    MLP_MFMA(qBh, qBl, qAh, qAl);                                           \
    MLP2_LOADW(3, qAh, qAl);                                                \
    MLP2_LOADB(3, qBh, qBl);                                                \
    MLP_MFMA(pBh, pBl, pAh, pAl);                                           \
    MLP_MFMA(qBh, qBl, qAh, qAl);

// ---------------- fused 2-layer MLP (layers 0,1) ----------------
__global__ __launch_bounds__(256, 3) void mlp_fused(
    const unsigned short* __restrict__ ah_g, const unsigned short* __restrict__ al_g,
    const unsigned short* __restrict__ w1h, const unsigned short* __restrict__ w1l,
    const float* __restrict__ b1,
    const unsigned short* __restrict__ w2h, const unsigned short* __restrict__ w2l,
    const float* __restrict__ b2,
    unsigned short* __restrict__ out, int N) {
    __shared__ unsigned short s_hh[64 * HSTR], s_hl[64 * HSTR];
    int tid = threadIdx.x;
    int lane = tid & 63, w = tid >> 6;
    int q = lane >> 4, lr = lane & 15;
    int wr = w >> 1, wc = w & 1;
    int n0 = blockIdx.x * 64;
    int nb0 = n0 + wc * 32 + lr;            // + j*16
    int rowc[2];
    rowc[0] = min(nb0, N - 1);
    rowc[1] = min(nb0 + 16, N - 1);

    MLP_PHASES_12();

    // epilogue 2: bias (no relu), single bf16, vector 8B stores
#pragma unroll
    for (int i = 0; i < 4; i++) {
        int hc0 = wr * 64 + i * 16 + q * 4;
        float4 bv = *(const float4*)(b2 + hc0);
        float bvr[4] = {bv.x, bv.y, bv.z, bv.w};
#pragma unroll
        for (int j = 0; j < 2; j++) {
            int node = nb0 + j * 16;
            if (node < N) {
                unsigned short o[4];
#pragma unroll
                for (int r = 0; r < 4; r++) o[r] = f2bf_hi(acc[i][j][r] + bvr[r]);
                *(ushort4*)&out[(size_t)node * DIM + hc0] = *(const ushort4*)&o[0];
            }
        }
    }
}

#define FIN3_LOADG(T, Bv_, Ah_, Al_) do {                                   \
    const unsigned short* asrc_ = srcs3[(T) >> 2];                          \
    int kk_ = ((T) & 3) * 32;                                               \
    _Pragma("unroll")                                                       \
    for (int j_ = 0; j_ < 2; j_++) {                                        \
        size_t ro_ = (size_t)rowc[j_] * DIM + kk_ + q * 8;                  \
        Bv_[j_] = *(const bf16x8*)(asrc_ + ro_);                            \
    }                                                                       \
    _Pragma("unroll")                                                       \
    for (int i_ = 0; i_ < 4; i_++) {                                        \
        size_t co_ = ((size_t)((T) * 8 + wr * 4 + i_) << 9) + lane * 8;     \
        Ah_[i_] = *(const bf16x8*)(fwh + co_);                              \
        Al_[i_] = *(const bf16x8*)(fwl + co_);                              \
    }                                                                       \
} while (0)

#define FIN_MFMA(Bv_, Ah_, Al_) do {                                        \
    _Pragma("unroll")                                                       \
    for (int i_ = 0; i_ < 4; i_++)                                          \
        _Pragma("unroll")                                                   \
        for (int j_ = 0; j_ < 2; j_++) {                                    \
            acc[i_][j_] = __builtin_amdgcn_mfma_f32_16x16x32_bf16(Ah_[i_], Bv_[j_], acc[i_][j_], 0, 0, 0); \
            acc[i_][j_] = __builtin_amdgcn_mfma_f32_16x16x32_bf16(Al_[i_], Bv_[j_], acc[i_][j_], 0, 0, 0); \
        }                                                                   \
} while (0)

// LDS-sourced final k-step (h3 hi+lo from s_hh/s_hl)
#define FIN3_STEPL(T) do {                                                  \
    int kk_ = ((T) - 12) * 32;                                              \
    bf16x8 Bh_[2], Bl_[2], Ah_[4], Al_[4];                                  \
    _Pragma("unroll")                                                       \
    for (int j_ = 0; j_ < 2; j_++) {                                        \
        int so_ = (wc * 32 + j_ * 16 + lr) * HSTR + kk_ + q * 8;            \
        Bh_[j_] = *(const bf16x8*)&s_hh[so_];                               \
        Bl_[j_] = *(const bf16x8*)&s_hl[so_];                               \
    }                                                                       \
    _Pragma("unroll")                                                       \
    for (int i_ = 0; i_ < 4; i_++) {                                        \
        size_t co_ = ((size_t)((T) * 8 + wr * 4 + i_) << 9) + lane * 8;     \
        Ah_[i_] = *(const bf16x8*)(fwh + co_);                              \
        Al_[i_] = *(const bf16x8*)(fwl + co_);                              \
    }                                                                       \
    _Pragma("unroll")                                                       \
    for (int i_ = 0; i_ < 4; i_++)                                          \
        _Pragma("unroll")                                                   \
        for (int j_ = 0; j_ < 2; j_++) {                                    \
            acc[i_][j_] = __builtin_amdgcn_mfma_f32_16x16x32_bf16(Ah_[i_], Bh_[j_], acc[i_][j_], 0, 0, 0); \
            acc[i_][j_] = __builtin_amdgcn_mfma_f32_16x16x32_bf16(Ah_[i_], Bl_[j_], acc[i_][j_], 0, 0, 0); \
            acc[i_][j_] = __builtin_amdgcn_mfma_f32_16x16x32_bf16(Al_[i_], Bh_[j_], acc[i_][j_], 0, 0, 0); \
        }                                                                   \
} while (0)

// ---------------- layer-2 MLP + final projection, fused ----------------
__global__ __launch_bounds__(256, 3) void mlp_final_fused(
    const unsigned short* __restrict__ ah_g, const unsigned short* __restrict__ al_g,
    const unsigned short* __restrict__ w1h, const unsigned short* __restrict__ w1l,
    const float* __restrict__ b1,
    const unsigned short* __restrict__ w2h, const unsigned short* __restrict__ w2l,
    const float* __restrict__ b2,
    const unsigned short* __restrict__ xsrc, const unsigned short* __restrict__ h0p,
    const unsigned short* __restrict__ h1p,
    const unsigned short* __restrict__ fwh, const unsigned short* __restrict__ fwl,
    const float* __restrict__ fbias, float* __restrict__ out, int N) {
    __shared__ unsigned short s_hh[64 * HSTR], s_hl[64 * HSTR];
    int tid = threadIdx.x;
    int lane = tid & 63, w = tid >> 6;
    int q = lane >> 4, lr = lane & 15;
    int wr = w >> 1, wc = w & 1;
    int n0 = blockIdx.x * 64;
    int nb0 = n0 + wc * 32 + lr;
    int rowc[2];
    rowc[0] = min(nb0, N - 1);
    rowc[1] = min(nb0 + 16, N - 1);

    MLP_PHASES_12();

    // all phase-2 LDS reads complete before h3 overwrites the buffer
    __syncthreads();

    // epilogue 2: h3 = acc + b2 (no relu), hi/lo split -> LDS (no global store)
#pragma unroll
    for (int i = 0; i < 4; i++) {
        int hc0 = wr * 64 + i * 16 + q * 4;
        float4 bv = *(const float4*)(b2 + hc0);
        float bvr[4] = {bv.x, bv.y, bv.z, bv.w};
#pragma unroll
        for (int j = 0; j < 2; j++) {
            int nl = wc * 32 + j * 16 + lr;
            unsigned short hh[4], hl[4];
#pragma unroll
            for (int r = 0; r < 4; r++) {
                float v = acc[i][j][r] + bvr[r];
                unsigned short h = f2bf_hi(v);
                hh[r] = h;
                hl[r] = f2bf_hi(v - bf2f(h));
            }
            *(ushort4*)&s_hh[nl * HSTR + hc0] = *(const ushort4*)&hh[0];
            *(ushort4*)&s_hl[nl * HSTR + hc0] = *(const ushort4*)&hl[0];
        }
    }

    // phase 3: out = [xb|h0|h1|h3] @ fw + fb
#pragma unroll
    for (int i = 0; i < 4; i++)
#pragma unroll
        for (int j = 0; j < 2; j++) acc[i][j] = (f32x4)(0.f);

    const unsigned short* srcs3[3] = {xsrc, h0p, h1p};
    bf16x8 pB[2], pWh[4], pWl[4];
    bf16x8 qB[2], qWh[4], qWl[4];
    // issue first global loads before the barrier (they don't touch LDS)
    FIN3_LOADG(0, pB, pWh, pWl);
    FIN3_LOADG(1, qB, qWh, qWl);
    __syncthreads();   // h3 LDS writes visible

#pragma unroll
    for (int t = 0; t < 12; t += 2) {
        FIN_MFMA(pB, pWh, pWl);
        if (t + 2 < 12) FIN3_LOADG(t + 2, pB, pWh, pWl);
        FIN_MFMA(qB, qWh, qWl);
        if (t + 3 < 12) FIN3_LOADG(t + 3, qB, qWh, qWl);
    }
    FIN3_STEPL(12);
    FIN3_STEPL(13);
    FIN3_STEPL(14);
    FIN3_STEPL(15);

    // final epilogue: fp32 + bias
#pragma unroll
    for (int i = 0; i < 4; i++) {
        int hc0 = wr * 64 + i * 16 + q * 4;
        float4 bv = *(const float4*)(fbias + hc0);
        float bvr[4] = {bv.x, bv.y, bv.z, bv.w};
#pragma unroll
        for (int j = 0; j < 2; j++) {
            int node = nb0 + j * 16;
            if (node < N) {
                float4 o;
                o.x = acc[i][j][0] + bvr[0];
                o.y = acc[i][j][1] + bvr[1];
                o.z = acc[i][j][2] + bvr[2];
                o.w = acc[i][j][3] + bvr[3];
                *(float4*)&out[(size_t)node * DIM + hc0] = o;
            }
        }
    }
}

extern "C" void kernel_launch(void* const* d_in, const int* in_sizes, int n_in,
                              void* d_out, int out_size, void* d_ws, size_t ws_size,
                              hipStream_t stream) {
    const float* x   = (const float*)d_in[0];
    const int* edge_index = (const int*)d_in[1];
    const float* ea  = (const float*)d_in[2];
    const float* lw  = (const float*)d_in[3];
    const float* lb  = (const float*)d_in[4];
    const float* eps = (const float*)d_in[5];
    const float* w1  = (const float*)d_in[6];
    const float* b1  = (const float*)d_in[7];
    const float* w2  = (const float*)d_in[8];
    const float* b2  = (const float*)d_in[9];
    const float* fw  = (const float*)d_in[10];
    const float* fb  = (const float*)d_in[11];
    float* out = (float*)d_out;

    const int N = NN, E = NE;
    const int* src = edge_index;
    const int* tgt = edge_index + E;
    const int NB = (N + 1023) / 1024;  // 49

    char* ws = (char*)d_ws;
    size_t off = 0;
    auto alloc = [&](size_t bytes) {
        void* p = ws + off;
        off += (bytes + 255) & ~(size_t)255;
        return p;
    };
    int*   counts  = (int*)alloc((size_t)N * 4);
    int*   offsets = (int*)alloc((size_t)(N + 1) * 4);
    int*   rank    = (int*)alloc((size_t)E * 4);
    int*   psum    = (int*)alloc((size_t)NB * 4);
    int*   pbase   = (int*)alloc((size_t)NB * 4);
    int2*  sedge   = (int2*)alloc((size_t)E * 8);
    unsigned short* w1t_h = (unsigned short*)alloc(49152 * 2);
    unsigned short* w1t_l = (unsigned short*)alloc(49152 * 2);
    unsigned short* w2t_h = (unsigned short*)alloc(49152 * 2);
    unsigned short* w2t_l = (unsigned short*)alloc(49152 * 2);
    unsigned short* fwt_h = (unsigned short*)alloc(65536 * 2);
    unsigned short* fwt_l = (unsigned short*)alloc(65536 * 2);
    unsigned short* xb    = (unsigned short*)alloc((size_t)N * DIM * 2);
    unsigned short* hbuf[2];
    for (int i = 0; i < 2; i++) hbuf[i] = (unsigned short*)alloc((size_t)N * DIM * 2);
    unsigned short* aggh = (unsigned short*)alloc((size_t)N * DIM * 2);
    unsigned short* aggl = (unsigned short*)alloc((size_t)N * DIM * 2);
    (void)ws_size; (void)in_sizes; (void)n_in; (void)out_size;

    const int PREP_T = ZERO_T + XCVT_T + 163840;
    prep_kernel<<<(PREP_T + 255) / 256, 256, 0, stream>>>(
        counts, x, xb, w1, w2, fw, w1t_h, w1t_l, w2t_h, w2t_l, fwt_h, fwt_l);
    rank_kernel<<<(E / 4 + 255) / 256, 256, 0, stream>>>(tgt, counts, rank, E);
    scan_partial_kernel<<<NB, 256, 0, stream>>>(counts, psum, N);
    scan_small_kernel<<<1, 64, 0, stream>>>(psum, pbase, offsets, NB, N);
    scan_apply_kernel<<<NB, 256, 0, stream>>>(counts, pbase, offsets, N);
    scatter2_kernel<<<(E / 4 + 255) / 256, 256, 0, stream>>>(src, tgt, ea, rank, offsets, sedge, E);

    const int GB = (N + 63) / 64;   // 782
    const int AB = (N + 15) / 16;   // 3125
    for (int l = 0; l < 2; l++) {
        const unsigned short* hin = (l == 0) ? xb : hbuf[l - 1];
        agg_kernel<<<AB, 256, 0, stream>>>(hin, offsets, sedge,
            lw + l * DIM, lb + l * DIM, eps, l, aggh, aggl, N);
        mlp_fused<<<GB, 256, 0, stream>>>(
            aggh, aggl,
            w1t_h + l * 16384, w1t_l + l * 16384, b1 + l * DIM,
            w2t_h + l * 16384, w2t_l + l * 16384, b2 + l * DIM,
            hbuf[l], N);
    }
    // layer 2 aggregation + fused MLP+final
    agg_kernel<<<AB, 256, 0, stream>>>(hbuf[1], offsets, sedge,
        lw + 2 * DIM, lb + 2 * DIM, eps, 2, aggh, aggl, N);
    mlp_final_fused<<<GB, 256, 0, stream>>>(
        aggh, aggl,
        w1t_h + 2 * 16384, w1t_l + 2 * 16384, b1 + 2 * DIM,
        w2t_h + 2 * 16384, w2t_l + 2 * 16384, b2 + 2 * DIM,
        xb, hbuf[0], hbuf[1], fwt_h, fwt_l, fb, out, N);
}